// Round 7
// baseline (2775.724 us; speedup 1.0000x reference)
//
#include <hip/hip_runtime.h>

typedef unsigned long long u64;
typedef unsigned int u32;

#define NB   8
#define NPC  8192
#define SS   2048
#define KK   32
#define CIN  64
#define NQ   (NB*SS)              // 16384
#define POS_OUT_OFF   (NQ*128)
#define BATCH_OUT_OFF (NQ*128 + NQ*3)
#define INF64 0x7ff0000000000000ULL
#define NCELL 512

// ---- f64-key helpers: key = (mind_bits<<32) | (8191-origIdx)<<13 | slot ----
// mind_bits <= 0x7f800000 and low!=garbage-NaN only when hi=0x7f800000&low!=0;
// inf keys exist only at init and are never folded (step 0 winner is forced).
// All folded keys are finite nonneg f64 patterns -> fmax == exact u64 max.
// f64 denormals are never flushed on CDNA, so tiny mind values compare exactly.

// 64-bit wave max via paired 32-bit DPP (gfx9 row_shr/row_bcast sequence).
__device__ __forceinline__ double wave64_max(double v) {
#define DPP_LVL(ctrl) { \
    int lo = __double2loint(v), hi = __double2hiint(v); \
    int tlo = __builtin_amdgcn_update_dpp(lo, lo, ctrl, 0xf, 0xf, false); \
    int thi = __builtin_amdgcn_update_dpp(hi, hi, ctrl, 0xf, 0xf, false); \
    v = fmax(v, __hiloint2double(thi, tlo)); }
    DPP_LVL(0x111) DPP_LVL(0x112) DPP_LVL(0x114) DPP_LVL(0x118)
    DPP_LVL(0x142) DPP_LVL(0x143)
#undef DPP_LVL
    return v;                       // valid in lane 63
}
// 16-lane (DPP row) max: rows are lane groups [0:16),[16:32),... aligned.
__device__ __forceinline__ double row16_max(double v) {
#define DPP_LVL(ctrl) { \
    int lo = __double2loint(v), hi = __double2hiint(v); \
    int tlo = __builtin_amdgcn_update_dpp(lo, lo, ctrl, 0xf, 0xf, false); \
    int thi = __builtin_amdgcn_update_dpp(hi, hi, ctrl, 0xf, 0xf, false); \
    v = fmax(v, __hiloint2double(thi, tlo)); }
    DPP_LVL(0x111) DPP_LVL(0x112) DPP_LVL(0x114) DPP_LVL(0x118)
#undef DPP_LVL
    return v;                       // valid in lanes 15,31,47,63
}

// ---------------- Kernel 1: cell-pruned exact farthest point sampling -------
// One block/cloud, 256 thr (4 waves). Points counting-sorted into 8^3 cells
// (LDS). Per step: fold 512 cell keys (per-wave, DPP) -> winner; cull cells
// where lb2(center,cellbox)*margin >= cellMax (exact skip: no point's mind
// can change); update only active cells' mind in LDS; per-cell key via
// row-DPP. Wave w owns cells with cid%4==w (A-reads/B-writes never cross).
__global__ __launch_bounds__(256) void fps_kernel(const float* __restrict__ pos,
                                                  float* __restrict__ out)
{
    __shared__ double cellKey[NCELL];
    __shared__ float sx[NPC], sy[NPC], sz[NPC];
    __shared__ float smind[NPC];
    __shared__ u32 cs[NCELL];            // inclusive prefix (cell ends)
    __shared__ u32 cnt_hist[1024];       // init: cnt[512]; loop: u16 hist[2048]
    __shared__ unsigned short sid[NPC];  // slot -> original index
    __shared__ unsigned short wact[4][128];
    __shared__ u32 ws0_sh;

    const int tid  = threadIdx.x;
    const int wid  = tid >> 6;
    const int lane = tid & 63;
    const int cloud = blockIdx.x;
    const float* cp = pos + (size_t)cloud * (NPC*3);

    // ---- init: histogram -> scan -> scatter ----
    u32* cnt = cnt_hist;
    for (int c = tid; c < NCELL; c += 256) cnt[c] = 0;
    __syncthreads();
    for (int i = tid; i < NPC; i += 256) {
        float x = cp[i*3+0], y = cp[i*3+1], z = cp[i*3+2];
        int cx = (int)(x*8.0f); cx = cx>7?7:cx;      // pos in [0,1)
        int cy = (int)(y*8.0f); cy = cy>7?7:cy;
        int cz = (int)(z*8.0f); cz = cz>7?7:cz;
        atomicAdd(&cnt[(cx<<6)|(cy<<3)|cz], 1u);
    }
    __syncthreads();
    {   // inclusive Hillis-Steele scan of cnt into cs (512 entries, 2/thread)
        int c0 = tid, c1 = tid + 256;
        cs[c0] = cnt[c0]; cs[c1] = cnt[c1];
        __syncthreads();
        for (int off = 1; off < NCELL; off <<= 1) {
            u32 v0 = cs[c0] + ((c0 >= off) ? cs[c0-off] : 0u);
            u32 v1 = cs[c1] + ((c1 >= off) ? cs[c1-off] : 0u);
            __syncthreads();
            cs[c0] = v0; cs[c1] = v1;
            __syncthreads();
        }
        // cnt := exclusive start (becomes running scatter ptr); init cellKey
        u32 e0 = cs[c0], s0 = e0 - cnt[c0];
        u32 e1 = cs[c1], s1 = e1 - cnt[c1];
        cnt[c0] = s0; cnt[c1] = s1;
        cellKey[c0] = (e0 > s0) ? __hiloint2double(0x7f800000, 0) : 0.0;
        cellKey[c1] = (e1 > s1) ? __hiloint2double(0x7f800000, 0) : 0.0;
    }
    __syncthreads();
    for (int i = tid; i < NPC; i += 256) {
        float x = cp[i*3+0], y = cp[i*3+1], z = cp[i*3+2];
        int cx = (int)(x*8.0f); cx = cx>7?7:cx;
        int cy = (int)(y*8.0f); cy = cy>7?7:cy;
        int cz = (int)(z*8.0f); cz = cz>7?7:cz;
        u32 slot = atomicAdd(&cnt[(cx<<6)|(cy<<3)|cz], 1u);
        sx[slot] = x; sy[slot] = y; sz[slot] = z;
        sid[slot] = (unsigned short)i;
        smind[slot] = __int_as_float(0x7f800000);
        if (i == 0) ws0_sh = slot;       // slot of original point 0
    }
    __syncthreads();

    // ---- main loop ----
    unsigned short* hist = (unsigned short*)cnt_hist;
    u32 ws = ws0_sh;
    const int g = lane >> 4, sub = lane & 15;
    const int cidA = (lane << 2) | wid, cidB = ((lane + 64) << 2) | wid;
    const float bxA = (float)((cidA>>6)&7)*0.125f - 1e-6f;
    const float byA = (float)((cidA>>3)&7)*0.125f - 1e-6f;
    const float bzA = (float)( cidA     &7)*0.125f - 1e-6f;
    const float bxB = (float)((cidB>>6)&7)*0.125f - 1e-6f;
    const float byB = (float)((cidB>>3)&7)*0.125f - 1e-6f;
    const float bzB = (float)( cidB     &7)*0.125f - 1e-6f;
    const float CW = 0.125f + 2e-6f;     // widened cell extent

    for (int s = 0; s < SS; ++s) {
        // C: per-wave fold of all 512 cell keys -> global winner (slot)
        if (s > 0) {
            double k0 = fmax(cellKey[lane      ], cellKey[lane + 64 ]);
            double k1 = fmax(cellKey[lane + 128], cellKey[lane + 192]);
            double k2 = fmax(cellKey[lane + 256], cellKey[lane + 320]);
            double k3 = fmax(cellKey[lane + 384], cellKey[lane + 448]);
            double k  = fmax(fmax(k0, k1), fmax(k2, k3));
            k = wave64_max(k);
            u32 lo = (u32)__builtin_amdgcn_readlane(__double2loint(k), 63);
            ws = lo & 8191u;
        }
        if (tid == 0) hist[s] = (unsigned short)ws;
        float ccx = sx[ws], ccy = sy[ws], ccz = sz[ws];   // broadcast reads
        __syncthreads();                 // bar1: all key reads done before writes

        // A: cull this wave's 128 cells (exact-conservative skip)
        float dxA = fmaxf(fmaxf(bxA - ccx, ccx - (bxA + CW)), 0.0f);
        float dyA = fmaxf(fmaxf(byA - ccy, ccy - (byA + CW)), 0.0f);
        float dzA = fmaxf(fmaxf(bzA - ccz, ccz - (bzA + CW)), 0.0f);
        float lbA = dxA*dxA + dyA*dyA + dzA*dzA;
        float cmA = __uint_as_float(((const u32*)&cellKey[cidA])[1]);
        bool aA = (lbA * 0.999996f) < cmA;
        float dxB = fmaxf(fmaxf(bxB - ccx, ccx - (bxB + CW)), 0.0f);
        float dyB = fmaxf(fmaxf(byB - ccy, ccy - (byB + CW)), 0.0f);
        float dzB = fmaxf(fmaxf(bzB - ccz, ccz - (bzB + CW)), 0.0f);
        float lbB = dxB*dxB + dyB*dyB + dzB*dzB;
        float cmB = __uint_as_float(((const u32*)&cellKey[cidB])[1]);
        bool aB = (lbB * 0.999996f) < cmB;
        u64 mA = __ballot(aA);
        u64 mB = __ballot(aB);
        u32 nA = (u32)__popcll(mA);
        if (aA) wact[wid][__popcll(mA & ((1ull<<lane)-1ull))]      = (unsigned short)cidA;
        if (aB) wact[wid][nA + __popcll(mB & ((1ull<<lane)-1ull))] = (unsigned short)cidB;
        u32 na = nA + (u32)__popcll(mB);

        // B: update active cells (16-lane group per cell, round-robin)
        for (u32 ai = (u32)g; ai < na; ai += 4) {
            int cid = wact[wid][ai];
            u32 st = (cid > 0) ? cs[cid-1] : 0u;
            u32 en = cs[cid];
            double fk = 0.0;
            for (u32 p = st + (u32)sub; p < en; p += 16) {
                float dx = __fsub_rn(sx[p], ccx);
                float dy = __fsub_rn(sy[p], ccy);
                float dz = __fsub_rn(sz[p], ccz);
                float d2 = __fadd_rn(__fadd_rn(__fmul_rn(dx,dx), __fmul_rn(dy,dy)),
                                     __fmul_rn(dz,dz));
                float m = fminf(smind[p], d2);
                smind[p] = m;
                u32 lowb = ((8191u - (u32)sid[p]) << 13) | p;
                fk = fmax(fk, __hiloint2double((int)__float_as_uint(m), (int)lowb));
            }
            fk = row16_max(fk);
            if (sub == 15) cellKey[cid] = fk;
        }
        __syncthreads();                 // bar2: writes visible for next fold
    }

    // ---- outputs ----
    float* qout = out + POS_OUT_OFF   + (size_t)cloud * SS * 3;
    float* bout = out + BATCH_OUT_OFF + (size_t)cloud * SS;
    for (int s2 = tid; s2 < SS; s2 += 256) {
        u32 w = hist[s2];
        qout[s2*3+0] = sx[w];
        qout[s2*3+1] = sy[w];
        qout[s2*3+2] = sz[w];
        bout[s2] = (float)cloud;
    }
}

// ---------------- Kernel 2: radius / 32 smallest-d2 selection ---------------
// Global-direct scan (cloud is L2-resident across the 64 blocks sharing it),
// ballot-compacted candidates in LDS, f64-key min extraction.
#define CAND_MAX 640
__global__ __launch_bounds__(256) void radius_kernel(const float* __restrict__ pos,
                                                     const float* __restrict__ out,
                                                     int* __restrict__ nidx,
                                                     int* __restrict__ ncnt)
{
    __shared__ u64 cand[4][CAND_MAX];
    const int tid  = threadIdx.x;
    const int wid  = tid >> 6;
    const int lane = tid & 63;
    const float R2 = (float)(0.2 * 0.2);        // float32(0.04) = 0x3D23D70A
    const float* qpos = out + POS_OUT_OFF;
    u64* cw = cand[wid];

    for (int qq = 0; qq < 4; ++qq) {
        const int q     = blockIdx.x*16 + wid*4 + qq;
        const int cloud = q >> 11;
        const float* cp = pos + (size_t)cloud * (NPC*3);
        float qx = qpos[q*3+0], qy = qpos[q*3+1], qz = qpos[q*3+2];

        int m = 0;
        for (int c = 0; c < NPC/64; ++c) {
            int j = c*64 + lane;
            float dx = __fsub_rn(cp[j*3+0], qx);
            float dy = __fsub_rn(cp[j*3+1], qy);
            float dz = __fsub_rn(cp[j*3+2], qz);
            float d2 = __fadd_rn(__fadd_rn(__fmul_rn(dx,dx), __fmul_rn(dy,dy)), __fmul_rn(dz,dz));
            bool in = (d2 <= R2);
            u64 mk = __ballot(in);
            if (in) {
                int p = m + __popcll(mk & ((1ull << lane) - 1ull));
                if (p < CAND_MAX) cw[p] = ((u64)__float_as_uint(d2) << 32) | (u32)j;
            }
            m += __popcll(mk);
        }
        if (m > CAND_MAX) m = CAND_MAX;

        double kk[10];
        #pragma unroll
        for (int t = 0; t < 10; ++t) {
            int p = t*64 + lane;
            kk[t] = (p < m) ? __longlong_as_double((long long)cw[p])
                            : __longlong_as_double((long long)INF64);
        }
        int cq = (m < KK) ? m : KK;
        int* nq = nidx + (size_t)q * KK;
        int j0 = 0;
        #pragma unroll 1
        for (int r = 0; r < KK; ++r) {
            double lmin = kk[0];
            #pragma unroll
            for (int t = 1; t < 10; ++t) lmin = fmin(lmin, kk[t]);
            #pragma unroll
            for (int off = 32; off >= 1; off >>= 1)
                lmin = fmin(lmin, __shfl_xor(lmin, off));
            u64 lb = (u64)__double_as_longlong(lmin);
            int j = (int)(u32)lb;
            if (r == 0) j0 = j;                 // center itself (d2=0) is first
            if (lane == 0) nq[r] = (lb == INF64) ? j0 : j;
            #pragma unroll
            for (int t = 0; t < 10; ++t)
                if ((u64)__double_as_longlong(kk[t]) == lb)
                    kk[t] = __longlong_as_double((long long)INF64);
        }
        if (lane == 0) ncnt[q] = cq;
    }
}

// ---------------- Kernel 3: gather + 3-layer MLP + masked max ---------------
// Weights/biases read straight from global with wave-uniform indices ->
// compiler emits s_load broadcasts (no LDS pipe pressure). feat in padded LDS.
__global__ __launch_bounds__(256) void mlp_kernel(const float* __restrict__ x,
                                                  const float* __restrict__ pos,
                                                  const float* __restrict__ W1, const float* __restrict__ b1,
                                                  const float* __restrict__ W2, const float* __restrict__ b2,
                                                  const float* __restrict__ W3, const float* __restrict__ b3,
                                                  const int* __restrict__ nidx, const int* __restrict__ ncnt,
                                                  float* __restrict__ out)
{
    __shared__ float flds[256*69];

    const int tid   = threadIdx.x;
    const int q     = blockIdx.x * 8 + (tid >> 5);
    const int slot  = tid & 31;
    const int cloud = q >> 11;
    const int j     = nidx[q*KK + slot];
    const bool valid = slot < ncnt[q];
    const size_t row = (size_t)cloud * NPC + (size_t)j;

    const float* qp = out + POS_OUT_OFF + (size_t)q*3;
    float qx = qp[0], qy = qp[1], qz = qp[2];

    float* myf = &flds[tid*69];
    {
        const float4* xr = (const float4*)(x + row*CIN);
        #pragma unroll
        for (int i = 0; i < 16; ++i) {
            float4 v = xr[i];
            myf[i*4+0]=v.x; myf[i*4+1]=v.y; myf[i*4+2]=v.z; myf[i*4+3]=v.w;
        }
        myf[64] = __fsub_rn(pos[row*3+0], qx);
        myf[65] = __fsub_rn(pos[row*3+1], qy);
        myf[66] = __fsub_rn(pos[row*3+2], qz);
    }
    // each thread reads only its own flds region: no barrier needed

    float acc[64];
    // ----- layer 1: 67 -> 64, relu -----
    #pragma unroll
    for (int o = 0; o < 64; ++o) acc[o] = b1[o];
    #pragma unroll 2
    for (int i = 0; i < 67; ++i) {
        float f = myf[i];
        const float4* wr = (const float4*)(W1 + i*64);
        #pragma unroll
        for (int o4 = 0; o4 < 16; ++o4) {
            float4 wv = wr[o4];
            acc[o4*4+0] = fmaf(f, wv.x, acc[o4*4+0]);
            acc[o4*4+1] = fmaf(f, wv.y, acc[o4*4+1]);
            acc[o4*4+2] = fmaf(f, wv.z, acc[o4*4+2]);
            acc[o4*4+3] = fmaf(f, wv.w, acc[o4*4+3]);
        }
    }
    #pragma unroll
    for (int o = 0; o < 64; ++o) myf[o] = fmaxf(acc[o], 0.0f);

    // ----- layer 2: 64 -> 64, relu -----
    #pragma unroll
    for (int o = 0; o < 64; ++o) acc[o] = b2[o];
    #pragma unroll 2
    for (int i = 0; i < 64; ++i) {
        float f = myf[i];
        const float4* wr = (const float4*)(W2 + i*64);
        #pragma unroll
        for (int o4 = 0; o4 < 16; ++o4) {
            float4 wv = wr[o4];
            acc[o4*4+0] = fmaf(f, wv.x, acc[o4*4+0]);
            acc[o4*4+1] = fmaf(f, wv.y, acc[o4*4+1]);
            acc[o4*4+2] = fmaf(f, wv.z, acc[o4*4+2]);
            acc[o4*4+3] = fmaf(f, wv.w, acc[o4*4+3]);
        }
    }
    #pragma unroll
    for (int o = 0; o < 64; ++o) myf[o] = fmaxf(acc[o], 0.0f);

    // ----- layer 3: 64 -> 128 (two halves), mask, max over 32 slots -----
    float* orow = out + (size_t)q*128;
    const float NEGINF = __int_as_float(0xff800000);
    for (int h = 0; h < 2; ++h) {
        #pragma unroll
        for (int o = 0; o < 64; ++o) acc[o] = b3[h*64 + o];
        const float* w3h = W3 + h*64;
        #pragma unroll 2
        for (int i = 0; i < 64; ++i) {
            float f = myf[i];
            const float4* wr = (const float4*)(w3h + i*128);
            #pragma unroll
            for (int o4 = 0; o4 < 16; ++o4) {
                float4 wv = wr[o4];
                acc[o4*4+0] = fmaf(f, wv.x, acc[o4*4+0]);
                acc[o4*4+1] = fmaf(f, wv.y, acc[o4*4+1]);
                acc[o4*4+2] = fmaf(f, wv.z, acc[o4*4+2]);
                acc[o4*4+3] = fmaf(f, wv.w, acc[o4*4+3]);
            }
        }
        #pragma unroll
        for (int o = 0; o < 64; ++o) if (!valid) acc[o] = NEGINF;
        #pragma unroll
        for (int off = 16; off >= 1; off >>= 1) {
            #pragma unroll
            for (int o = 0; o < 64; ++o) acc[o] = fmaxf(acc[o], __shfl_xor(acc[o], off));
        }
        if (slot == 0) {
            #pragma unroll
            for (int o = 0; o < 64; o += 4) {
                float4 v = make_float4(acc[o], acc[o+1], acc[o+2], acc[o+3]);
                *(float4*)&orow[h*64+o] = v;
            }
        }
    }
}

// ------------------------------- launcher -----------------------------------
extern "C" void kernel_launch(void* const* d_in, const int* in_sizes, int n_in,
                              void* d_out, int out_size, void* d_ws, size_t ws_size,
                              hipStream_t stream) {
    const float* x   = (const float*)d_in[0];
    const float* pos = (const float*)d_in[1];
    // d_in[2]=batch (implicit), d_in[3]=num_samples (K=32 hardcoded)
    const float* W1 = (const float*)d_in[4];
    const float* b1 = (const float*)d_in[5];
    const float* W2 = (const float*)d_in[6];
    const float* b2 = (const float*)d_in[7];
    const float* W3 = (const float*)d_in[8];
    const float* b3 = (const float*)d_in[9];
    float* out = (float*)d_out;

    int* nidx = (int*)d_ws;                  // NQ*KK ints (2 MiB)
    int* ncnt = nidx + (size_t)NQ*KK;        // NQ ints

    hipLaunchKernelGGL(fps_kernel,    dim3(NB),      dim3(256), 0, stream, pos, out);
    hipLaunchKernelGGL(radius_kernel, dim3(NQ/16),   dim3(256), 0, stream, pos, out, nidx, ncnt);
    hipLaunchKernelGGL(mlp_kernel,    dim3(NQ/8),    dim3(256), 0, stream,
                       x, pos, W1, b1, W2, b2, W3, b3, nidx, ncnt, out);
}